// Round 20
// baseline (438.622 us; speedup 1.0000x reference)
//
#include <hip/hip_runtime.h>
#include <cstdio>

#define N_TOK 16384
#define CDIM  512

typedef unsigned short ushort_t;
typedef _Float16 f16;
typedef __attribute__((ext_vector_type(8))) _Float16 f16x8;
typedef __attribute__((ext_vector_type(4))) _Float16 f16x4;
typedef __attribute__((ext_vector_type(2))) _Float16 f16x2;
typedef __attribute__((ext_vector_type(4))) float f32x4;

// ---------------------------------------------------------------- helpers
__device__ __forceinline__ float fast_pow(float x, float p) {
  return __builtin_amdgcn_exp2f(p * __builtin_amdgcn_logf(x));
}
__device__ __forceinline__ void gl_lds16(const void* g, void* l) {
  __builtin_amdgcn_global_load_lds((const __attribute__((address_space(1))) void*)g,
                                   (__attribute__((address_space(3))) void*)l, 16, 0, 0);
}
// permuted fp16 column index (must match cvt_perm_kernel): row r, col k
__device__ __forceinline__ int perm_col(int k, int r) {
  const int kg = k >> 5, c8 = (k >> 3) & 3, e = k & 7;
  return kg * 32 + ((c8 ^ ((r >> 1) & 3)) * 8) + e;
}

// ---------------------------------------------------------------- zero
__global__ void zero_kernel(float* __restrict__ p, int n) {
  int i = blockIdx.x * blockDim.x + threadIdx.x;
  if (i < n) p[i] = 0.f;
}

// ---------------------------------------------------------------- 1/softplus(scale), 512 values
__global__ void sp_kernel(const float* __restrict__ scale, float* __restrict__ inv_s) {
  int i = blockIdx.x * blockDim.x + threadIdx.x;
  if (i < 512) {
    float sc = scale[i];
    float s = (sc > 20.f) ? sc : log1pf(expf(sc));
    inv_s[i] = 1.0f / s;
  }
}

// ---------------------------------------------------------------- fp32 -> fp16, chunk-permuted (512-col rows)
__global__ __launch_bounds__(256) void cvt_perm_kernel(const float* __restrict__ in,
                                                       f16* __restrict__ out, int n4) {
  int i = blockIdx.x * blockDim.x + threadIdx.x;
  const int stride = gridDim.x * blockDim.x;
  for (; i < n4; i += stride) {
    float4 v = ((const float4*)in)[i];
    const int r = i >> 7;
    const int f = i & 127;
    const int kg = f >> 3;
    const int c = (f >> 1) & 3;
    const int e = (f & 1) * 4;
    const int dst = r * 512 + kg * 32 + ((c ^ ((r >> 1) & 3)) * 8) + e;
    f16x4 h;
    h.x = (f16)v.x; h.y = (f16)v.y; h.z = (f16)v.z; h.w = (f16)v.w;
    *(f16x4*)&out[dst] = h;
  }
}

// ---------------------------------------------------------------- fp16 MFMA GEMM, full-DMA, 3-buffer counted-vmcnt
// (R19 proven: waits BEFORE barrier; overwrite after the barrier retiring
// that buffer's readers; tail waits vmcnt(0).)
template <int OUT16, int KK>
__global__ __launch_bounds__(256, 3) void gemm_f16(const f16* __restrict__ A,
                                                   const f16* __restrict__ Bw,
                                                   const float* __restrict__ b1,
                                                   const float* __restrict__ b2,
                                                   float* __restrict__ C32,
                                                   f16* __restrict__ C16,
                                                   const int nY,
                                                   const int ncol1, const int ldc) {
  __shared__ __align__(16) f16 SMEM[24576];   // 3x(A 4096 | B 4096) = 48 KB
  const int t = threadIdx.x;
  const int lane = t & 63;
  const int w = t >> 6;
  const int wr = w >> 1, wc = w & 1;

  const int id = blockIdx.x;
  const int xcd = id & 7;
  const int j = id >> 3;
  const int xpc = (int)(gridDim.x) / (nY * 8);
  const int xloc = j / nY;
  const int y = j - xloc * nY;
  const size_t bm = (size_t)(xcd * xpc + xloc) * 128;
  const int bn = y * 128;

  const int lr = lane & 15;
  const int ksl = lane >> 4;

  f32x4 acc[4][4] = {};

  auto stage = [&](int k0, int buf) {
    const int rsub = lane >> 2;
    const int csub = (lane & 3) * 8;
    const size_t ga = (bm + w * 32 + rsub) * (size_t)KK + k0 + csub;
    const size_t gb = ((size_t)(bn + w * 32 + rsub)) * KK + k0 + csub;
    f16* Ab = SMEM + buf * 4096;
    f16* Bb = SMEM + 12288 + buf * 4096;
    gl_lds16(A + ga,                    Ab + (w * 32) * 32);
    gl_lds16(A + ga + 16 * (size_t)KK,  Ab + (w * 32 + 16) * 32);
    gl_lds16(Bw + gb,                   Bb + (w * 32) * 32);
    gl_lds16(Bw + gb + 16 * (size_t)KK, Bb + (w * 32 + 16) * 32);
  };

  constexpr int nsteps = KK >> 5;
  stage(0, 0);
  stage(32, 1);
#pragma unroll
  for (int s = 0; s < nsteps; ++s) {
    const int buf = s % 3;
    if (s + 1 < nsteps) {
      asm volatile("s_waitcnt vmcnt(4)" ::: "memory");   // stage(s) landed; s+1 in flight
    } else {
      asm volatile("s_waitcnt vmcnt(0)" ::: "memory");   // tail: stage(s) landed
    }
    asm volatile("s_waitcnt lgkmcnt(0)" ::: "memory");   // my reads of buf[s-1] retired
    __builtin_amdgcn_sched_barrier(0);
    __builtin_amdgcn_s_barrier();                        // publish both globally
    __builtin_amdgcn_sched_barrier(0);
    if (s + 2 < nsteps) stage((s + 2) << 5, (s + 2) % 3);   // overwrite buf[s-1]
    const f16* Ab = SMEM + buf * 4096;
    const f16* Bb = SMEM + 12288 + buf * 4096;
    f16x8 a[4], b[4];
#pragma unroll
    for (int i = 0; i < 4; ++i) {
      const int rA = wr * 64 + i * 16 + lr;
      a[i] = *(const f16x8*)&Ab[rA * 32 + ((ksl ^ ((rA >> 1) & 3)) * 8)];
      const int rB = wc * 64 + i * 16 + lr;
      b[i] = *(const f16x8*)&Bb[rB * 32 + ((ksl ^ ((rB >> 1) & 3)) * 8)];
    }
#pragma unroll
    for (int mi = 0; mi < 4; ++mi)
#pragma unroll
      for (int ni = 0; ni < 4; ++ni)
        acc[mi][ni] = __builtin_amdgcn_mfma_f32_16x16x32_f16(a[mi], b[ni], acc[mi][ni], 0, 0, 0);
  }

  const int rg = (lane >> 4) << 2;
  if (OUT16) {
    __syncthreads();   // full drain before SMEM reuse
#pragma unroll
    for (int ni = 0; ni < 4; ++ni) {
      const int cl = wc * 64 + ni * 16 + lr;
      const int cg = bn + cl;
      const float bs = (cg < ncol1) ? b1[cg] : b2[cg - ncol1];
#pragma unroll
      for (int mi = 0; mi < 4; ++mi)
#pragma unroll
        for (int j2 = 0; j2 < 4; ++j2)
          SMEM[(wr * 64 + mi * 16 + rg + j2) * 132 + cl] = (f16)(acc[mi][ni][j2] + bs);
    }
    __syncthreads();
#pragma unroll
    for (int i = 0; i < 8; ++i) {
      const int idx = i * 256 + t;
      const int rl = idx >> 4, ch = (idx & 15) * 8;
      *(f16x8*)&C16[(bm + rl) * (size_t)ldc + bn + ch] = *(const f16x8*)&SMEM[rl * 132 + ch];
    }
  } else {
#pragma unroll
    for (int ni = 0; ni < 4; ++ni) {
      const int col = bn + wc * 64 + ni * 16 + lr;
      const float bs = (col < ncol1) ? b1[col] : b2[col - ncol1];
#pragma unroll
      for (int mi = 0; mi < 4; ++mi) {
        float* Cp = C32 + (bm + wr * 64 + mi * 16 + rg) * (size_t)ldc + col;
#pragma unroll
        for (int j2 = 0; j2 < 4; ++j2)
          Cp[(size_t)j2 * ldc] = acc[mi][ni][j2] + bs;
      }
    }
  }
}

// ---------------------------------------------------------------- nonlinearity, wave-per-row, fp16 in-place
__global__ __launch_bounds__(256) void nonlin16_kernel(f16* __restrict__ qkv,
                                                       const float* __restrict__ inv_s,
                                                       const float* __restrict__ ff) {
  const int t = threadIdx.x, lane = t & 63, w = t >> 6;
  const int row = blockIdx.x * 4 + w;
  f16* qr = qkv + (size_t)row * 1536 + lane * 8;
  f16* kr = qr + 512;
  f16x8 qh = *(const f16x8*)qr;
  f16x8 kh = *(const f16x8*)kr;
  float is[8], fv[8];
  *(float4*)&is[0] = *(const float4*)(inv_s + lane * 8);
  *(float4*)&is[4] = *(const float4*)(inv_s + lane * 8 + 4);
  *(float4*)&fv[0] = *(const float4*)(ff + lane * 8);
  *(float4*)&fv[4] = *(const float4*)(ff + lane * 8 + 4);

  float qv[8], kval[8], sq = 0.f, sk = 0.f;
#pragma unroll
  for (int i = 0; i < 8; ++i) {
    qv[i] = (fmaxf((float)qh[i], 0.f) + 1e-6f) * is[i];
    kval[i] = (fmaxf((float)kh[i], 0.f) + 1e-6f) * is[i];
    sq += qv[i] * qv[i];
    sk += kval[i] * kval[i];
  }
#pragma unroll
  for (int off = 1; off < 64; off <<= 1) {
    sq += __shfl_xor(sq, off);
    sk += __shfl_xor(sk, off);
  }
  const float qn = sqrtf(sq), kn = sqrtf(sk);

  float pq[8], pk[8], sq2 = 0.f, sk2 = 0.f;
#pragma unroll
  for (int i = 0; i < 8; ++i) {
    pq[i] = fast_pow(qv[i], fv[i]);
    pk[i] = fast_pow(kval[i], fv[i]);
    sq2 += pq[i] * pq[i];
    sk2 += pk[i] * pk[i];
  }
#pragma unroll
  for (int off = 1; off < 64; off <<= 1) {
    sq2 += __shfl_xor(sq2, off);
    sk2 += __shfl_xor(sk2, off);
  }
  const float qs = qn / sqrtf(sq2), ks = kn / sqrtf(sk2);
  f16x8 qo, ko;
#pragma unroll
  for (int i = 0; i < 8; ++i) {
    qo[i] = (f16)(pq[i] * qs);
    ko[i] = (f16)(pk[i] * ks);
  }
  *(f16x8*)qr = qo;
  *(f16x8*)kr = ko;
}

// ---------------------------------------------------------------- kv_mat via MFMA (+ fused ksum)  (R16 proven)
__global__ __launch_bounds__(256) void kvmat_mfma_kernel(const f16* __restrict__ qkv,
                                                         float* __restrict__ kvm,
                                                         float* __restrict__ ksum) {
  __shared__ __align__(16) f16 ST[20480];   // 4 waves x (kT,vT)[64][40] = 40 KB
  const int bh = blockIdx.y;
  const int b = bh >> 3, h = bh & 7;
  const int chunk = blockIdx.x;
  const int t = threadIdx.x, lane = t & 63, w = t >> 6;
  f16* kT = ST + w * 5120;
  f16* vT = kT + 2560;
  const int tok = lane & 31, half = lane >> 5;
  const int lr = lane & 15, ksl = lane >> 4;
  f32x4 acc[4][4] = {};
  float kacc[4] = {0.f, 0.f, 0.f, 0.f};
  const int rowbase = b * N_TOK + chunk * 512 + w * 128;

  for (int s = 0; s < 4; ++s) {
    const size_t g = (size_t)(rowbase + s * 32 + tok) * 1536 + 512 + h * 64 + half * 32;
    f16x8 kr[4], vr[4];
#pragma unroll
    for (int j = 0; j < 4; ++j) {
      kr[j] = *(const f16x8*)&qkv[g + j * 8];
      vr[j] = *(const f16x8*)&qkv[g + 512 + j * 8];
    }
#pragma unroll
    for (int j = 0; j < 4; ++j)
#pragma unroll
      for (int e = 0; e < 8; ++e) {
        const int ch = half * 32 + j * 8 + e;
        kT[ch * 40 + tok] = kr[j][e];
        vT[ch * 40 + tok] = vr[j][e];
      }
    f16x8 a[4], bv[4];
#pragma unroll
    for (int mi = 0; mi < 4; ++mi)
      a[mi] = *(const f16x8*)&kT[(mi * 16 + lr) * 40 + ksl * 8];
#pragma unroll
    for (int ni = 0; ni < 4; ++ni)
      bv[ni] = *(const f16x8*)&vT[(ni * 16 + lr) * 40 + ksl * 8];
#pragma unroll
    for (int mi = 0; mi < 4; ++mi) {
      float s8 = 0.f;
#pragma unroll
      for (int e = 0; e < 8; ++e) s8 += (float)a[mi][e];
      kacc[mi] += s8;
    }
#pragma unroll
    for (int mi = 0; mi < 4; ++mi)
#pragma unroll
      for (int ni = 0; ni < 4; ++ni)
        acc[mi][ni] = __builtin_amdgcn_mfma_f32_16x16x32_f16(a[mi], bv[ni], acc[mi][ni], 0, 0, 0);
  }

#pragma unroll
  for (int mi = 0; mi < 4; ++mi) {
    kacc[mi] += __shfl_xor(kacc[mi], 16);
    kacc[mi] += __shfl_xor(kacc[mi], 32);
  }
  if (ksl == 0) {
#pragma unroll
    for (int mi = 0; mi < 4; ++mi)
      atomicAdd(&ksum[b * 512 + h * 64 + mi * 16 + lr], kacc[mi]);
  }

  float* tile = (float*)ST;
  const int rg = (lane >> 4) << 2;
  __syncthreads();
  for (int ww = 0; ww < 4; ++ww) {
    if (w == ww) {
#pragma unroll
      for (int mi = 0; mi < 4; ++mi)
#pragma unroll
        for (int ni = 0; ni < 4; ++ni)
#pragma unroll
          for (int j2 = 0; j2 < 4; ++j2) {
            const int aidx = (mi * 16 + rg + j2) * 66 + ni * 16 + lr;
            tile[aidx] = (ww == 0) ? acc[mi][ni][j2] : tile[aidx] + acc[mi][ni][j2];
          }
    }
    __syncthreads();
  }
  const float scl = 1.0f / (float)N_TOK;
#pragma unroll
  for (int i = 0; i < 16; ++i) {
    const int idx = i * 256 + t;
    const int rr = idx >> 6, cc = idx & 63;
    atomicAdd(&kvm[(size_t)bh * 4096 + idx], tile[rr * 66 + cc] * scl);
  }
}

// ---------------------------------------------------------------- kvm fp32 -> transposed, chunk-swizzled fp16
__global__ void cvt_kvmT_kernel(const float* __restrict__ kvm, f16* __restrict__ kvmT16) {
  const int bh = blockIdx.x, t = threadIdx.x;
#pragma unroll
  for (int i = 0; i < 16; ++i) {
    const int e = i * 256 + t;            // 0..4095 = din*64 + d
    const int din = e >> 6, d = e & 63;
    const float v = kvm[(size_t)bh * 4096 + e];
    const int c = din >> 3, ce = din & 7;
    kvmT16[(size_t)bh * 4096 + d * 64 + ((c ^ (d & 7)) * 8) + ce] = (f16)v;
  }
}

// ---------------------------------------------------------------- MFMA attention (R14 proven) + setprio
__global__ __launch_bounds__(256, 4) void attn_mfma_kernel(const f16* __restrict__ qkv,
                                                           const f16* __restrict__ kvmT16,
                                                           const float* __restrict__ ksum,
                                                           f16* __restrict__ y16) {
  __shared__ __align__(16) f16 QS[128 * 64];   // [row][chunk ^ (row&7)]
  __shared__ __align__(16) f16 KM[64 * 64];    // [d][chunk ^ (d&7)] (pre-swizzled)
  __shared__ float kms[64];
  __shared__ float zl[128];
  const int bh = blockIdx.y;
  const int b = bh >> 3, h = bh & 7;
  const int tok0 = blockIdx.x * 128;
  const int t = threadIdx.x, lane = t & 63, w = t >> 6;

#pragma unroll
  for (int i = 0; i < 4; ++i) {
    const int idx = i * 256 + t;
    const int row = idx >> 3, ch = idx & 7;
    const f16x8 v = *(const f16x8*)&qkv[((size_t)(b * N_TOK) + tok0 + row) * 1536 + h * 64 + ch * 8];
    *(f16x8*)&QS[row * 64 + ((ch ^ (row & 7)) * 8)] = v;
  }
#pragma unroll
  for (int i = 0; i < 2; ++i) {
    const int idx = i * 256 + t;
    *(f16x8*)&KM[idx * 8] = *(const f16x8*)&kvmT16[(size_t)bh * 4096 + idx * 8];
  }
  if (t < 64) kms[t] = ksum[b * 512 + h * 64 + t];
  __syncthreads();

  {
    const int tok = t >> 1;
    const int ch0 = (t & 1) * 4;
    float p = 0.f;
#pragma unroll
    for (int c = 0; c < 4; ++c) {
      const int ch = ch0 + c;
      const f16x8 hv = *(const f16x8*)&QS[tok * 64 + ((ch ^ (tok & 7)) * 8)];
#pragma unroll
      for (int e = 0; e < 8; ++e) p += (float)hv[e] * kms[ch * 8 + e];
    }
    p += __shfl_xor(p, 1);
    if ((t & 1) == 0) zl[tok] = 1.0f / (p * (1.0f / (float)N_TOK) + 1e-6f);
  }
  __syncthreads();

  const int lr = lane & 15, ksl = lane >> 4;
  f32x4 acc[2][4] = {};
  __builtin_amdgcn_s_setprio(1);
#pragma unroll
  for (int s = 0; s < 2; ++s) {
    f16x8 a[2], bfr[4];
#pragma unroll
    for (int mi = 0; mi < 2; ++mi) {
      const int row = w * 32 + mi * 16 + lr;
      a[mi] = *(const f16x8*)&QS[row * 64 + (((s * 4 + ksl) ^ (row & 7)) * 8)];
    }
#pragma unroll
    for (int ni = 0; ni < 4; ++ni) {
      const int dr = ni * 16 + lr;
      bfr[ni] = *(const f16x8*)&KM[dr * 64 + (((s * 4 + ksl) ^ (dr & 7)) * 8)];
    }
#pragma unroll
    for (int mi = 0; mi < 2; ++mi)
#pragma unroll
      for (int ni = 0; ni < 4; ++ni)
        acc[mi][ni] = __builtin_amdgcn_mfma_f32_16x16x32_f16(a[mi], bfr[ni], acc[mi][ni], 0, 0, 0);
  }
  __builtin_amdgcn_s_setprio(0);

  const int rg = (lane >> 4) << 2;
#pragma unroll
  for (int mi = 0; mi < 2; ++mi)
#pragma unroll
    for (int ni = 0; ni < 4; ++ni)
#pragma unroll
      for (int j2 = 0; j2 < 4; ++j2) {
        const int row = w * 32 + mi * 16 + rg + j2;
        const int dcol = ni * 16 + lr;
        const float val = acc[mi][ni][j2] * zl[row];
        const int r = (int)(b * N_TOK) + tok0 + row;
        y16[(size_t)r * 512 + perm_col(h * 64 + dcol, r)] = (f16)val;
      }
}

// ---------------------------------------------------------------- depthwise 5x5 conv on v (fp16 in), RMW perm y16
// Channel-quad XOR swizzle on vt (key = halo-x & 3, quad-granular so float4
// staging stays 16B-aligned; reads use the same key) -> per-tap start banks
// double: ~4-way conflicts become ~2-way (free).
__global__ __launch_bounds__(256, 4) void conv_kernel(const f16* __restrict__ qkv,
                                                      f16* __restrict__ y16,
                                                      const float* __restrict__ wconv,
                                                      const float* __restrict__ bconv) {
  __shared__ float vt[20 * 20 * 16];
  const int zidx = blockIdx.z;
  const int bh = zidx >> 2, cq = zidx & 3;
  const int b = bh >> 3, h = bh & 7;
  const int c0 = cq * 16;
  const int tx0 = blockIdx.x * 16, ty0 = blockIdx.y * 16;
  const int t = threadIdx.x;
  const size_t vcol = 1024 + h * 64 + c0;
#pragma unroll
  for (int i = 0; i < 7; ++i) {
    const int idx = i * 256 + t;
    if (idx < 1600) {
      const int pix = idx >> 2, q = idx & 3;      // channel quad 0..3
      const int lx = pix % 20, ly = pix / 20;
      const int gx = tx0 + lx - 2, gy = ty0 + ly - 2;
      float4 val = make_float4(0.f, 0.f, 0.f, 0.f);
      if ((unsigned)gx < 128u && (unsigned)gy < 128u) {
        f16x4 hv = *(const f16x4*)&qkv[((size_t)(b * N_TOK) + gy * 128 + gx) * 1536 + vcol + q * 4];
        val = make_float4((float)hv.x, (float)hv.y, (float)hv.z, (float)hv.w);
      }
      *(float4*)&vt[pix * 16 + ((q ^ (lx & 3)) << 2)] = val;   // swizzled quad slot
    }
  }
  const int c2i = t & 7;               // channel-pair index 0..7
  const int dd0 = c0 + c2i * 2;
  const int qsel = c2i >> 1;           // quad of this pair
  const int low = (c2i & 1) * 2;       // float offset within quad
  float w0[25], w1[25];
#pragma unroll
  for (int k = 0; k < 25; ++k) {
    w0[k] = wconv[dd0 * 25 + k];
    w1[k] = wconv[(dd0 + 1) * 25 + k];
  }
  const float bb0 = bconv[dd0], bb1 = bconv[dd0 + 1];
  __syncthreads();
  const int slot = t >> 3;             // 32 pixel slots
  const int col = h * 64 + dd0;
  for (int i = 0; i < 8; ++i) {
    const int pix = i * 32 + slot;
    const int px = pix & 15, py = pix >> 4;
    float a0 = bb0, a1 = bb1;
#pragma unroll
    for (int ky = 0; ky < 5; ++ky)
#pragma unroll
      for (int kx = 0; kx < 5; ++kx) {
        const int lxt = px + kx;       // halo x (matches staging key)
        const float2 v2 = *(const float2*)&vt[((py + ky) * 20 + lxt) * 16 +
                                              ((qsel ^ (lxt & 3)) << 2) + low];
        a0 = fmaf(w0[ky * 5 + kx], v2.x, a0);
        a1 = fmaf(w1[ky * 5 + kx], v2.y, a1);
      }
    const int r = (int)(b * N_TOK) + (ty0 + py) * 128 + (tx0 + px);
    f16* p = &y16[(size_t)r * 512 + perm_col(col, r)];
    f16x2 old = *(f16x2*)p;
    old.x = (f16)((float)old.x + a0);
    old.y = (f16)((float)old.y + a1);
    *(f16x2*)p = old;
  }
}

// ---------------------------------------------------------------- launch
extern "C" void kernel_launch(void* const* d_in, const int* in_sizes, int n_in,
                              void* d_out, int out_size, void* d_ws, size_t ws_size,
                              hipStream_t stream) {
  (void)n_in; (void)out_size;
  const float* x     = (const float*)d_in[0];
  const float* Wq    = (const float*)d_in[1];
  const float* bq    = (const float*)d_in[2];
  const float* Wkv   = (const float*)d_in[3];
  const float* bkv   = (const float*)d_in[4];
  const float* Wp    = (const float*)d_in[5];
  const float* bp    = (const float*)d_in[6];
  const float* ff    = (const float*)d_in[7];
  const float* scale = (const float*)d_in[8];
  const float* dwc_w = (const float*)d_in[9];
  const float* dwc_b = (const float*)d_in[10];

  const int B = in_sizes[0] / (N_TOK * CDIM);   // 4
  const int M = B * N_TOK;                      // 65536

  // ws layout: qkv16 [M][1536] fp16 | y16 [M][512] fp16 perm | ksum | kvm | scratch
  f16*   qkv16 = (f16*)d_ws;
  f16*   y16   = qkv16 + (size_t)M * 1536;
  float* ksum  = (float*)(y16 + (size_t)M * 512);
  float* kvm   = ksum + (size_t)B * 512;
  float* zscr  = kvm + (size_t)B * 8 * 4096;

  size_t need = ((size_t)M * 1536 + (size_t)B * 512 + (size_t)B * 8 * 4096 +
                 (size_t)B * 8 * N_TOK) * sizeof(float);   // known-good bound
  if (ws_size < need) {
    fprintf(stderr, "kernel_launch: ws too small (%zu < %zu)\n", ws_size, need);
    return;
  }

  // d_out head carve (dead until final GEMM): x16 (64 MB) + wqkv16 (1.5 MB)
  f16* x16    = (f16*)d_out;
  f16* wqkv16 = x16 + (size_t)M * 512;
  // z-scratch carve: wp16 (512 KB) + inv_s (2 KB) + kvmT16 (256 KB)
  f16* wp16    = (f16*)zscr;
  float* inv_s = zscr + 131072;
  f16* kvmT16  = (f16*)(inv_s + 512);

  const int nsmall = B * 512 + B * 8 * 4096;
  zero_kernel<<<(nsmall + 255) / 256, 256, 0, stream>>>(ksum, nsmall);
  sp_kernel<<<2, 256, 0, stream>>>(scale, inv_s);
  cvt_perm_kernel<<<4096, 256, 0, stream>>>(x, x16, M * 512 / 4);
  cvt_perm_kernel<<<256, 256, 0, stream>>>(Wq, wqkv16, 512 * 512 / 4);
  cvt_perm_kernel<<<512, 256, 0, stream>>>(Wkv, wqkv16 + 512 * 512, 1024 * 512 / 4);
  cvt_perm_kernel<<<256, 256, 0, stream>>>(Wp, wp16, 512 * 512 / 4);

  // fused q+kv projection -> fp16 qkv16 [M][1536] (raw, pre-nonlin)
  gemm_f16<1, CDIM><<<(M / 128) * 12, 256, 0, stream>>>(x16, wqkv16, bq, bkv,
                                                        nullptr, qkv16, 12, 512, 1536);

  nonlin16_kernel<<<M / 4, 256, 0, stream>>>(qkv16, inv_s, ff);
  kvmat_mfma_kernel<<<dim3(32, B * 8), 256, 0, stream>>>(qkv16, kvm, ksum);
  cvt_kvmT_kernel<<<B * 8, 256, 0, stream>>>(kvm, kvmT16);
  attn_mfma_kernel<<<dim3(N_TOK / 128, B * 8), 256, 0, stream>>>(qkv16, kvmT16, ksum, y16);
  conv_kernel<<<dim3(8, 8, B * 8 * 4), 256, 0, stream>>>(qkv16, y16, dwc_w, dwc_b);

  // output projection: fp32 into d_out (overwrites dead x16/wqkv16)
  gemm_f16<0, CDIM><<<(M / 128) * 4, 256, 0, stream>>>(y16, wp16, bp, bp,
                                                       (float*)d_out, nullptr, 4, 512, 512);
}

// Round 21
// 421.722 us; speedup vs baseline: 1.0401x; 1.0401x over previous
//
#include <hip/hip_runtime.h>
#include <cstdio>

#define N_TOK 16384
#define CDIM  512

typedef unsigned short ushort_t;
typedef _Float16 f16;
typedef __attribute__((ext_vector_type(8))) _Float16 f16x8;
typedef __attribute__((ext_vector_type(4))) _Float16 f16x4;
typedef __attribute__((ext_vector_type(2))) _Float16 f16x2;
typedef __attribute__((ext_vector_type(4))) float f32x4;

// ---------------------------------------------------------------- helpers
__device__ __forceinline__ float fast_pow(float x, float p) {
  return __builtin_amdgcn_exp2f(p * __builtin_amdgcn_logf(x));
}
__device__ __forceinline__ void gl_lds16(const void* g, void* l) {
  __builtin_amdgcn_global_load_lds((const __attribute__((address_space(1))) void*)g,
                                   (__attribute__((address_space(3))) void*)l, 16, 0, 0);
}
// permuted fp16 column index (must match cvt_perm): row r, col k
__device__ __forceinline__ int perm_col(int k, int r) {
  const int kg = k >> 5, c8 = (k >> 3) & 3, e = k & 7;
  return kg * 32 + ((c8 ^ ((r >> 1) & 3)) * 8) + e;
}

// ---------------------------------------------------------------- fused prep: zero(ksum|kvm) + 1/softplus + weight cvt_perm
// grid 1024x256 = 262144 threads; thread i converts one float4 of {Wq|Wkv|Wp}.
__global__ __launch_bounds__(256) void prep_kernel(const float* __restrict__ scale,
                                                   const float* __restrict__ Wq,
                                                   const float* __restrict__ Wkv,
                                                   const float* __restrict__ Wp,
                                                   float* __restrict__ zero_base, int nzero,
                                                   float* __restrict__ inv_s,
                                                   f16* __restrict__ wqkv16,
                                                   f16* __restrict__ wp16) {
  const int i = blockIdx.x * 256 + threadIdx.x;     // 0..262143
  for (int z = i; z < nzero; z += 262144) zero_base[z] = 0.f;
  if (i < 512) {
    const float sc = scale[i];
    const float s = (sc > 20.f) ? sc : log1pf(expf(sc));
    inv_s[i] = 1.0f / s;
  }
  const float* src; f16* dst; int local;
  if (i < 65536)       { src = Wq;  dst = wqkv16;          local = i; }
  else if (i < 196608) { src = Wkv; dst = wqkv16 + 262144; local = i - 65536; }
  else                 { src = Wp;  dst = wp16;            local = i - 196608; }
  const float4 v = ((const float4*)src)[local];
  const int r = local >> 7;
  const int f = local & 127;
  const int kg = f >> 3;
  const int c = (f >> 1) & 3;
  const int e = (f & 1) * 4;
  const int off = r * 512 + kg * 32 + ((c ^ ((r >> 1) & 3)) * 8) + e;
  f16x4 h;
  h.x = (f16)v.x; h.y = (f16)v.y; h.z = (f16)v.z; h.w = (f16)v.w;
  *(f16x4*)&dst[off] = h;
}

// ---------------------------------------------------------------- fp32 -> fp16, chunk-permuted (512-col rows)
__global__ __launch_bounds__(256) void cvt_perm_kernel(const float* __restrict__ in,
                                                       f16* __restrict__ out, int n4) {
  int i = blockIdx.x * blockDim.x + threadIdx.x;
  const int stride = gridDim.x * blockDim.x;
  for (; i < n4; i += stride) {
    float4 v = ((const float4*)in)[i];
    const int r = i >> 7;
    const int f = i & 127;
    const int kg = f >> 3;
    const int c = (f >> 1) & 3;
    const int e = (f & 1) * 4;
    const int dst = r * 512 + kg * 32 + ((c ^ ((r >> 1) & 3)) * 8) + e;
    f16x4 h;
    h.x = (f16)v.x; h.y = (f16)v.y; h.z = (f16)v.z; h.w = (f16)v.w;
    *(f16x4*)&out[dst] = h;
  }
}

// ---------------------------------------------------------------- fp16 MFMA GEMM, full-DMA, 3-buffer counted-vmcnt
// (R19 proven: waits BEFORE barrier; overwrite after the barrier retiring
// that buffer's readers; tail waits vmcnt(0).)
template <int OUT16, int KK>
__global__ __launch_bounds__(256, 3) void gemm_f16(const f16* __restrict__ A,
                                                   const f16* __restrict__ Bw,
                                                   const float* __restrict__ b1,
                                                   const float* __restrict__ b2,
                                                   float* __restrict__ C32,
                                                   f16* __restrict__ C16,
                                                   const int nY,
                                                   const int ncol1, const int ldc) {
  __shared__ __align__(16) f16 SMEM[24576];   // 3x(A 4096 | B 4096) = 48 KB
  const int t = threadIdx.x;
  const int lane = t & 63;
  const int w = t >> 6;
  const int wr = w >> 1, wc = w & 1;

  const int id = blockIdx.x;
  const int xcd = id & 7;
  const int j = id >> 3;
  const int xpc = (int)(gridDim.x) / (nY * 8);
  const int xloc = j / nY;
  const int y = j - xloc * nY;
  const size_t bm = (size_t)(xcd * xpc + xloc) * 128;
  const int bn = y * 128;

  const int lr = lane & 15;
  const int ksl = lane >> 4;

  f32x4 acc[4][4] = {};

  auto stage = [&](int k0, int buf) {
    const int rsub = lane >> 2;
    const int csub = (lane & 3) * 8;
    const size_t ga = (bm + w * 32 + rsub) * (size_t)KK + k0 + csub;
    const size_t gb = ((size_t)(bn + w * 32 + rsub)) * KK + k0 + csub;
    f16* Ab = SMEM + buf * 4096;
    f16* Bb = SMEM + 12288 + buf * 4096;
    gl_lds16(A + ga,                    Ab + (w * 32) * 32);
    gl_lds16(A + ga + 16 * (size_t)KK,  Ab + (w * 32 + 16) * 32);
    gl_lds16(Bw + gb,                   Bb + (w * 32) * 32);
    gl_lds16(Bw + gb + 16 * (size_t)KK, Bb + (w * 32 + 16) * 32);
  };

  constexpr int nsteps = KK >> 5;
  stage(0, 0);
  stage(32, 1);
#pragma unroll
  for (int s = 0; s < nsteps; ++s) {
    const int buf = s % 3;
    if (s + 1 < nsteps) {
      asm volatile("s_waitcnt vmcnt(4)" ::: "memory");   // stage(s) landed; s+1 in flight
    } else {
      asm volatile("s_waitcnt vmcnt(0)" ::: "memory");   // tail: stage(s) landed
    }
    asm volatile("s_waitcnt lgkmcnt(0)" ::: "memory");   // my reads of buf[s-1] retired
    __builtin_amdgcn_sched_barrier(0);
    __builtin_amdgcn_s_barrier();                        // publish both globally
    __builtin_amdgcn_sched_barrier(0);
    if (s + 2 < nsteps) stage((s + 2) << 5, (s + 2) % 3);   // overwrite buf[s-1]
    const f16* Ab = SMEM + buf * 4096;
    const f16* Bb = SMEM + 12288 + buf * 4096;
    f16x8 a[4], b[4];
#pragma unroll
    for (int i = 0; i < 4; ++i) {
      const int rA = wr * 64 + i * 16 + lr;
      a[i] = *(const f16x8*)&Ab[rA * 32 + ((ksl ^ ((rA >> 1) & 3)) * 8)];
      const int rB = wc * 64 + i * 16 + lr;
      b[i] = *(const f16x8*)&Bb[rB * 32 + ((ksl ^ ((rB >> 1) & 3)) * 8)];
    }
#pragma unroll
    for (int mi = 0; mi < 4; ++mi)
#pragma unroll
      for (int ni = 0; ni < 4; ++ni)
        acc[mi][ni] = __builtin_amdgcn_mfma_f32_16x16x32_f16(a[mi], b[ni], acc[mi][ni], 0, 0, 0);
  }

  const int rg = (lane >> 4) << 2;
  if (OUT16) {
    __syncthreads();   // full drain before SMEM reuse
#pragma unroll
    for (int ni = 0; ni < 4; ++ni) {
      const int cl = wc * 64 + ni * 16 + lr;
      const int cg = bn + cl;
      const float bs = (cg < ncol1) ? b1[cg] : b2[cg - ncol1];
#pragma unroll
      for (int mi = 0; mi < 4; ++mi)
#pragma unroll
        for (int j2 = 0; j2 < 4; ++j2)
          SMEM[(wr * 64 + mi * 16 + rg + j2) * 132 + cl] = (f16)(acc[mi][ni][j2] + bs);
    }
    __syncthreads();
#pragma unroll
    for (int i = 0; i < 8; ++i) {
      const int idx = i * 256 + t;
      const int rl = idx >> 4, ch = (idx & 15) * 8;
      *(f16x8*)&C16[(bm + rl) * (size_t)ldc + bn + ch] = *(const f16x8*)&SMEM[rl * 132 + ch];
    }
  } else {
#pragma unroll
    for (int ni = 0; ni < 4; ++ni) {
      const int col = bn + wc * 64 + ni * 16 + lr;
      const float bs = (col < ncol1) ? b1[col] : b2[col - ncol1];
#pragma unroll
      for (int mi = 0; mi < 4; ++mi) {
        float* Cp = C32 + (bm + wr * 64 + mi * 16 + rg) * (size_t)ldc + col;
#pragma unroll
        for (int j2 = 0; j2 < 4; ++j2)
          Cp[(size_t)j2 * ldc] = acc[mi][ni][j2] + bs;
      }
    }
  }
}

// ---------------------------------------------------------------- nonlinearity, wave-per-row, fp16 in-place
__global__ __launch_bounds__(256) void nonlin16_kernel(f16* __restrict__ qkv,
                                                       const float* __restrict__ inv_s,
                                                       const float* __restrict__ ff) {
  const int t = threadIdx.x, lane = t & 63, w = t >> 6;
  const int row = blockIdx.x * 4 + w;
  f16* qr = qkv + (size_t)row * 1536 + lane * 8;
  f16* kr = qr + 512;
  f16x8 qh = *(const f16x8*)qr;
  f16x8 kh = *(const f16x8*)kr;
  float is[8], fv[8];
  *(float4*)&is[0] = *(const float4*)(inv_s + lane * 8);
  *(float4*)&is[4] = *(const float4*)(inv_s + lane * 8 + 4);
  *(float4*)&fv[0] = *(const float4*)(ff + lane * 8);
  *(float4*)&fv[4] = *(const float4*)(ff + lane * 8 + 4);

  float qv[8], kval[8], sq = 0.f, sk = 0.f;
#pragma unroll
  for (int i = 0; i < 8; ++i) {
    qv[i] = (fmaxf((float)qh[i], 0.f) + 1e-6f) * is[i];
    kval[i] = (fmaxf((float)kh[i], 0.f) + 1e-6f) * is[i];
    sq += qv[i] * qv[i];
    sk += kval[i] * kval[i];
  }
#pragma unroll
  for (int off = 1; off < 64; off <<= 1) {
    sq += __shfl_xor(sq, off);
    sk += __shfl_xor(sk, off);
  }
  const float qn = sqrtf(sq), kn = sqrtf(sk);

  float pq[8], pk[8], sq2 = 0.f, sk2 = 0.f;
#pragma unroll
  for (int i = 0; i < 8; ++i) {
    pq[i] = fast_pow(qv[i], fv[i]);
    pk[i] = fast_pow(kval[i], fv[i]);
    sq2 += pq[i] * pq[i];
    sk2 += pk[i] * pk[i];
  }
#pragma unroll
  for (int off = 1; off < 64; off <<= 1) {
    sq2 += __shfl_xor(sq2, off);
    sk2 += __shfl_xor(sk2, off);
  }
  const float qs = qn / sqrtf(sq2), ks = kn / sqrtf(sk2);
  f16x8 qo, ko;
#pragma unroll
  for (int i = 0; i < 8; ++i) {
    qo[i] = (f16)(pq[i] * qs);
    ko[i] = (f16)(pk[i] * ks);
  }
  *(f16x8*)qr = qo;
  *(f16x8*)kr = ko;
}

// ---------------------------------------------------------------- kv_mat via MFMA (+ fused ksum)  (R16 proven)
__global__ __launch_bounds__(256) void kvmat_mfma_kernel(const f16* __restrict__ qkv,
                                                         float* __restrict__ kvm,
                                                         float* __restrict__ ksum) {
  __shared__ __align__(16) f16 ST[20480];   // 4 waves x (kT,vT)[64][40] = 40 KB
  const int bh = blockIdx.y;
  const int b = bh >> 3, h = bh & 7;
  const int chunk = blockIdx.x;
  const int t = threadIdx.x, lane = t & 63, w = t >> 6;
  f16* kT = ST + w * 5120;
  f16* vT = kT + 2560;
  const int tok = lane & 31, half = lane >> 5;
  const int lr = lane & 15, ksl = lane >> 4;
  f32x4 acc[4][4] = {};
  float kacc[4] = {0.f, 0.f, 0.f, 0.f};
  const int rowbase = b * N_TOK + chunk * 512 + w * 128;

  for (int s = 0; s < 4; ++s) {
    const size_t g = (size_t)(rowbase + s * 32 + tok) * 1536 + 512 + h * 64 + half * 32;
    f16x8 kr[4], vr[4];
#pragma unroll
    for (int j = 0; j < 4; ++j) {
      kr[j] = *(const f16x8*)&qkv[g + j * 8];
      vr[j] = *(const f16x8*)&qkv[g + 512 + j * 8];
    }
#pragma unroll
    for (int j = 0; j < 4; ++j)
#pragma unroll
      for (int e = 0; e < 8; ++e) {
        const int ch = half * 32 + j * 8 + e;
        kT[ch * 40 + tok] = kr[j][e];
        vT[ch * 40 + tok] = vr[j][e];
      }
    f16x8 a[4], bv[4];
#pragma unroll
    for (int mi = 0; mi < 4; ++mi)
      a[mi] = *(const f16x8*)&kT[(mi * 16 + lr) * 40 + ksl * 8];
#pragma unroll
    for (int ni = 0; ni < 4; ++ni)
      bv[ni] = *(const f16x8*)&vT[(ni * 16 + lr) * 40 + ksl * 8];
#pragma unroll
    for (int mi = 0; mi < 4; ++mi) {
      float s8 = 0.f;
#pragma unroll
      for (int e = 0; e < 8; ++e) s8 += (float)a[mi][e];
      kacc[mi] += s8;
    }
#pragma unroll
    for (int mi = 0; mi < 4; ++mi)
#pragma unroll
      for (int ni = 0; ni < 4; ++ni)
        acc[mi][ni] = __builtin_amdgcn_mfma_f32_16x16x32_f16(a[mi], bv[ni], acc[mi][ni], 0, 0, 0);
  }

#pragma unroll
  for (int mi = 0; mi < 4; ++mi) {
    kacc[mi] += __shfl_xor(kacc[mi], 16);
    kacc[mi] += __shfl_xor(kacc[mi], 32);
  }
  if (ksl == 0) {
#pragma unroll
    for (int mi = 0; mi < 4; ++mi)
      atomicAdd(&ksum[b * 512 + h * 64 + mi * 16 + lr], kacc[mi]);
  }

  float* tile = (float*)ST;
  const int rg = (lane >> 4) << 2;
  __syncthreads();
  for (int ww = 0; ww < 4; ++ww) {
    if (w == ww) {
#pragma unroll
      for (int mi = 0; mi < 4; ++mi)
#pragma unroll
        for (int ni = 0; ni < 4; ++ni)
#pragma unroll
          for (int j2 = 0; j2 < 4; ++j2) {
            const int aidx = (mi * 16 + rg + j2) * 66 + ni * 16 + lr;
            tile[aidx] = (ww == 0) ? acc[mi][ni][j2] : tile[aidx] + acc[mi][ni][j2];
          }
    }
    __syncthreads();
  }
  const float scl = 1.0f / (float)N_TOK;
#pragma unroll
  for (int i = 0; i < 16; ++i) {
    const int idx = i * 256 + t;
    const int rr = idx >> 6, cc = idx & 63;
    atomicAdd(&kvm[(size_t)bh * 4096 + idx], tile[rr * 66 + cc] * scl);
  }
}

// ---------------------------------------------------------------- kvm fp32 -> transposed, chunk-swizzled fp16
__global__ void cvt_kvmT_kernel(const float* __restrict__ kvm, f16* __restrict__ kvmT16) {
  const int bh = blockIdx.x, t = threadIdx.x;
#pragma unroll
  for (int i = 0; i < 16; ++i) {
    const int e = i * 256 + t;            // 0..4095 = din*64 + d
    const int din = e >> 6, d = e & 63;
    const float v = kvm[(size_t)bh * 4096 + e];
    const int c = din >> 3, ce = din & 7;
    kvmT16[(size_t)bh * 4096 + d * 64 + ((c ^ (d & 7)) * 8) + ce] = (f16)v;
  }
}

// ---------------------------------------------------------------- MFMA attention (R14 proven) + setprio
__global__ __launch_bounds__(256, 4) void attn_mfma_kernel(const f16* __restrict__ qkv,
                                                           const f16* __restrict__ kvmT16,
                                                           const float* __restrict__ ksum,
                                                           f16* __restrict__ y16) {
  __shared__ __align__(16) f16 QS[128 * 64];   // [row][chunk ^ (row&7)]
  __shared__ __align__(16) f16 KM[64 * 64];    // [d][chunk ^ (d&7)] (pre-swizzled)
  __shared__ float kms[64];
  __shared__ float zl[128];
  const int bh = blockIdx.y;
  const int b = bh >> 3, h = bh & 7;
  const int tok0 = blockIdx.x * 128;
  const int t = threadIdx.x, lane = t & 63, w = t >> 6;

#pragma unroll
  for (int i = 0; i < 4; ++i) {
    const int idx = i * 256 + t;
    const int row = idx >> 3, ch = idx & 7;
    const f16x8 v = *(const f16x8*)&qkv[((size_t)(b * N_TOK) + tok0 + row) * 1536 + h * 64 + ch * 8];
    *(f16x8*)&QS[row * 64 + ((ch ^ (row & 7)) * 8)] = v;
  }
#pragma unroll
  for (int i = 0; i < 2; ++i) {
    const int idx = i * 256 + t;
    *(f16x8*)&KM[idx * 8] = *(const f16x8*)&kvmT16[(size_t)bh * 4096 + idx * 8];
  }
  if (t < 64) kms[t] = ksum[b * 512 + h * 64 + t];
  __syncthreads();

  {
    const int tok = t >> 1;
    const int ch0 = (t & 1) * 4;
    float p = 0.f;
#pragma unroll
    for (int c = 0; c < 4; ++c) {
      const int ch = ch0 + c;
      const f16x8 hv = *(const f16x8*)&QS[tok * 64 + ((ch ^ (tok & 7)) * 8)];
#pragma unroll
      for (int e = 0; e < 8; ++e) p += (float)hv[e] * kms[ch * 8 + e];
    }
    p += __shfl_xor(p, 1);
    if ((t & 1) == 0) zl[tok] = 1.0f / (p * (1.0f / (float)N_TOK) + 1e-6f);
  }
  __syncthreads();

  const int lr = lane & 15, ksl = lane >> 4;
  f32x4 acc[2][4] = {};
  __builtin_amdgcn_s_setprio(1);
#pragma unroll
  for (int s = 0; s < 2; ++s) {
    f16x8 a[2], bfr[4];
#pragma unroll
    for (int mi = 0; mi < 2; ++mi) {
      const int row = w * 32 + mi * 16 + lr;
      a[mi] = *(const f16x8*)&QS[row * 64 + (((s * 4 + ksl) ^ (row & 7)) * 8)];
    }
#pragma unroll
    for (int ni = 0; ni < 4; ++ni) {
      const int dr = ni * 16 + lr;
      bfr[ni] = *(const f16x8*)&KM[dr * 64 + (((s * 4 + ksl) ^ (dr & 7)) * 8)];
    }
#pragma unroll
    for (int mi = 0; mi < 2; ++mi)
#pragma unroll
      for (int ni = 0; ni < 4; ++ni)
        acc[mi][ni] = __builtin_amdgcn_mfma_f32_16x16x32_f16(a[mi], bfr[ni], acc[mi][ni], 0, 0, 0);
  }
  __builtin_amdgcn_s_setprio(0);

  const int rg = (lane >> 4) << 2;
#pragma unroll
  for (int mi = 0; mi < 2; ++mi)
#pragma unroll
    for (int ni = 0; ni < 4; ++ni)
#pragma unroll
      for (int j2 = 0; j2 < 4; ++j2) {
        const int row = w * 32 + mi * 16 + rg + j2;
        const int dcol = ni * 16 + lr;
        const float val = acc[mi][ni][j2] * zl[row];
        const int r = (int)(b * N_TOK) + tok0 + row;
        y16[(size_t)r * 512 + perm_col(h * 64 + dcol, r)] = (f16)val;
      }
}

// ---------------------------------------------------------------- depthwise 5x5 conv on v (fp16 in), RMW perm y16
// (R19 proven: 2 channels/thread, float2 vt reads, paired f16x2 RMW)
__global__ __launch_bounds__(256, 4) void conv_kernel(const f16* __restrict__ qkv,
                                                      f16* __restrict__ y16,
                                                      const float* __restrict__ wconv,
                                                      const float* __restrict__ bconv) {
  __shared__ float vt[20 * 20 * 16];
  const int zidx = blockIdx.z;
  const int bh = zidx >> 2, cq = zidx & 3;
  const int b = bh >> 3, h = bh & 7;
  const int c0 = cq * 16;
  const int tx0 = blockIdx.x * 16, ty0 = blockIdx.y * 16;
  const int t = threadIdx.x;
  const size_t vcol = 1024 + h * 64 + c0;
#pragma unroll
  for (int i = 0; i < 7; ++i) {
    const int idx = i * 256 + t;
    if (idx < 1600) {
      const int pix = idx >> 2, c4 = (idx & 3) * 4;
      const int lx = pix % 20, ly = pix / 20;
      const int gx = tx0 + lx - 2, gy = ty0 + ly - 2;
      float4 val = make_float4(0.f, 0.f, 0.f, 0.f);
      if ((unsigned)gx < 128u && (unsigned)gy < 128u) {
        f16x4 hv = *(const f16x4*)&qkv[((size_t)(b * N_TOK) + gy * 128 + gx) * 1536 + vcol + c4];
        val = make_float4((float)hv.x, (float)hv.y, (float)hv.z, (float)hv.w);
      }
      *(float4*)&vt[pix * 16 + c4] = val;
    }
  }
  const int c2 = (t & 7) * 2;          // channel pair 0,2,...,14
  const int dd0 = c0 + c2;
  float w0[25], w1[25];
#pragma unroll
  for (int k = 0; k < 25; ++k) {
    w0[k] = wconv[dd0 * 25 + k];
    w1[k] = wconv[(dd0 + 1) * 25 + k];
  }
  const float bb0 = bconv[dd0], bb1 = bconv[dd0 + 1];
  __syncthreads();
  const int slot = t >> 3;             // 32 pixel slots
  const int col = h * 64 + dd0;
  for (int i = 0; i < 8; ++i) {
    const int pix = i * 32 + slot;
    const int px = pix & 15, py = pix >> 4;
    float a0 = bb0, a1 = bb1;
#pragma unroll
    for (int ky = 0; ky < 5; ++ky)
#pragma unroll
      for (int kx = 0; kx < 5; ++kx) {
        const float2 v2 = *(const float2*)&vt[((py + ky) * 20 + (px + kx)) * 16 + c2];
        a0 = fmaf(w0[ky * 5 + kx], v2.x, a0);
        a1 = fmaf(w1[ky * 5 + kx], v2.y, a1);
      }
    const int r = (int)(b * N_TOK) + (ty0 + py) * 128 + (tx0 + px);
    f16* p = &y16[(size_t)r * 512 + perm_col(col, r)];
    f16x2 old = *(f16x2*)p;
    old.x = (f16)((float)old.x + a0);
    old.y = (f16)((float)old.y + a1);
    *(f16x2*)p = old;
  }
}

// ---------------------------------------------------------------- launch
extern "C" void kernel_launch(void* const* d_in, const int* in_sizes, int n_in,
                              void* d_out, int out_size, void* d_ws, size_t ws_size,
                              hipStream_t stream) {
  (void)n_in; (void)out_size;
  const float* x     = (const float*)d_in[0];
  const float* Wq    = (const float*)d_in[1];
  const float* bq    = (const float*)d_in[2];
  const float* Wkv   = (const float*)d_in[3];
  const float* bkv   = (const float*)d_in[4];
  const float* Wp    = (const float*)d_in[5];
  const float* bp    = (const float*)d_in[6];
  const float* ff    = (const float*)d_in[7];
  const float* scale = (const float*)d_in[8];
  const float* dwc_w = (const float*)d_in[9];
  const float* dwc_b = (const float*)d_in[10];

  const int B = in_sizes[0] / (N_TOK * CDIM);   // 4
  const int M = B * N_TOK;                      // 65536

  // ws layout: qkv16 [M][1536] fp16 | y16 [M][512] fp16 perm | ksum | kvm | scratch
  f16*   qkv16 = (f16*)d_ws;
  f16*   y16   = qkv16 + (size_t)M * 1536;
  float* ksum  = (float*)(y16 + (size_t)M * 512);
  float* kvm   = ksum + (size_t)B * 512;
  float* zscr  = kvm + (size_t)B * 8 * 4096;

  size_t need = ((size_t)M * 1536 + (size_t)B * 512 + (size_t)B * 8 * 4096 +
                 (size_t)B * 8 * N_TOK) * sizeof(float);   // known-good bound
  if (ws_size < need) {
    fprintf(stderr, "kernel_launch: ws too small (%zu < %zu)\n", ws_size, need);
    return;
  }

  // d_out head carve (dead until final GEMM): x16 (64 MB) + wqkv16 (1.5 MB)
  f16* x16    = (f16*)d_out;
  f16* wqkv16 = x16 + (size_t)M * 512;
  // z-scratch carve: wp16 (512 KB) + inv_s (2 KB) + kvmT16 (256 KB)
  f16* wp16    = (f16*)zscr;
  float* inv_s = zscr + 131072;
  f16* kvmT16  = (f16*)(inv_s + 512);

  const int nsmall = B * 512 + B * 8 * 4096;   // ksum + kvm contiguous
  prep_kernel<<<1024, 256, 0, stream>>>(scale, Wq, Wkv, Wp, ksum, nsmall,
                                        inv_s, wqkv16, wp16);
  cvt_perm_kernel<<<4096, 256, 0, stream>>>(x, x16, M * 512 / 4);

  // fused q+kv projection -> fp16 qkv16 [M][1536] (raw, pre-nonlin)
  gemm_f16<1, CDIM><<<(M / 128) * 12, 256, 0, stream>>>(x16, wqkv16, bq, bkv,
                                                        nullptr, qkv16, 12, 512, 1536);

  nonlin16_kernel<<<M / 4, 256, 0, stream>>>(qkv16, inv_s, ff);
  kvmat_mfma_kernel<<<dim3(32, B * 8), 256, 0, stream>>>(qkv16, kvm, ksum);
  cvt_kvmT_kernel<<<B * 8, 256, 0, stream>>>(kvm, kvmT16);
  attn_mfma_kernel<<<dim3(N_TOK / 128, B * 8), 256, 0, stream>>>(qkv16, kvmT16, ksum, y16);
  conv_kernel<<<dim3(8, 8, B * 8 * 4), 256, 0, stream>>>(qkv16, y16, dwc_w, dwc_b);

  // output projection: fp32 into d_out (overwrites dead x16/wqkv16)
  gemm_f16<0, CDIM><<<(M / 128) * 4, 256, 0, stream>>>(y16, wp16, bp, bp,
                                                       (float*)d_out, nullptr, 4, 512, 512);
}